// Round 3
// baseline (511.535 us; speedup 1.0000x reference)
//
#include <hip/hip_runtime.h>
#include <math.h>

#define NL 6
#define NB 6
#define NS 7
#define ND 512
#define NH 8
#define HDIM 64
#define NFF 2048
#define NROWS (NB*NS)   // 42

// 11 rows of msg/ctx that are actually consumed downstream:
// rows 1..6  (batch 0, s=1..6)  -> agg_noun
// rows 7,14,21,28,35 (s=0 of b=1..5) -> agg_verb
__device__ __constant__ int NRQ[11] = {1,2,3,4,5,6,7,14,21,28,35};

__device__ __forceinline__ float wave_sum(float v) {
    v += __shfl_down(v, 32, 64);
    v += __shfl_down(v, 16, 64);
    v += __shfl_down(v, 8, 64);
    v += __shfl_down(v, 4, 64);
    v += __shfl_down(v, 2, 64);
    v += __shfl_down(v, 1, 64);
    return v;
}

__device__ __forceinline__ float wave_sum_all(float v) {
    v += __shfl_xor(v, 32, 64);
    v += __shfl_xor(v, 16, 64);
    v += __shfl_xor(v, 8, 64);
    v += __shfl_xor(v, 4, 64);
    v += __shfl_xor(v, 2, 64);
    v += __shfl_xor(v, 1, 64);
    return v;
}

// per-lane partial dot of a 512-length vector: lane handles 8 consecutive floats
__device__ __forceinline__ float dot512(const float* __restrict__ a,
                                        const float* __restrict__ b, int lane) {
    int d0 = lane * 8;
    float4 a1 = *(const float4*)(a + d0);
    float4 a2 = *(const float4*)(a + d0 + 4);
    float4 b1 = *(const float4*)(b + d0);
    float4 b2 = *(const float4*)(b + d0 + 4);
    return a1.x*b1.x + a1.y*b1.y + a1.z*b1.z + a1.w*b1.w
         + a2.x*b2.x + a2.y*b2.y + a2.z*b2.z + a2.w*b2.w;
}

__device__ __forceinline__ float dot2048(const float* __restrict__ a,
                                         const float* __restrict__ b, int lane) {
    float acc = 0.f;
    for (int c = 0; c < 4; c++) acc += dot512(a + c*ND, b + c*ND, lane);
    return acc;
}

// Load source row (x with role tokens added) for qkv, as 8 floats per lane.
// For b==0 and l>0 the row is LN(ff_prev[s]) with the previous layer's ln2/ln4.
__device__ __forceinline__ void load_src(int b, int s, int lane, int l,
    const float* __restrict__ features, const float* __restrict__ role,
    const float* __restrict__ ffprev,
    const float* __restrict__ l2w, const float* __restrict__ l2b,
    const float* __restrict__ l4w, const float* __restrict__ l4b,
    float4& s1, float4& s2)
{
    int d0 = lane * 8;
    if (b > 0 || l == 0) {
        const float* src = features + (size_t)(b*NS + s) * ND + d0;
        s1 = *(const float4*)src;
        s2 = *(const float4*)(src + 4);
    } else {
        const float* fp = ffprev + s * ND + d0;
        float4 f1 = *(const float4*)fp;
        float4 f2 = *(const float4*)(fp + 4);
        float sum = f1.x+f1.y+f1.z+f1.w + f2.x+f2.y+f2.z+f2.w;
        sum = wave_sum_all(sum);
        float mu = sum * (1.f/ND);
        f1.x-=mu; f1.y-=mu; f1.z-=mu; f1.w-=mu;
        f2.x-=mu; f2.y-=mu; f2.z-=mu; f2.w-=mu;
        float sq = f1.x*f1.x+f1.y*f1.y+f1.z*f1.z+f1.w*f1.w
                 + f2.x*f2.x+f2.y*f2.y+f2.z*f2.z+f2.w*f2.w;
        sq = wave_sum_all(sq);
        float inv = rsqrtf(sq*(1.f/ND) + 1e-5f);
        const float* w  = (s == 0) ? l4w : l2w;
        const float* bb = (s == 0) ? l4b : l2b;
        float4 w1 = *(const float4*)(w + d0),  w2 = *(const float4*)(w + d0 + 4);
        float4 b1 = *(const float4*)(bb + d0), b2 = *(const float4*)(bb + d0 + 4);
        s1.x = f1.x*inv*w1.x + b1.x; s1.y = f1.y*inv*w1.y + b1.y;
        s1.z = f1.z*inv*w1.z + b1.z; s1.w = f1.w*inv*w1.w + b1.w;
        s2.x = f2.x*inv*w2.x + b2.x; s2.y = f2.y*inv*w2.y + b2.y;
        s2.z = f2.z*inv*w2.z + b2.z; s2.w = f2.w*inv*w2.w + b2.w;
    }
    if (s > 0) {
        const float* rp = role + (size_t)(b*(NS-1) + (s-1)) * ND + d0;
        float4 r1 = *(const float4*)rp;
        float4 r2 = *(const float4*)(rp + 4);
        s1.x += r1.x; s1.y += r1.y; s1.z += r1.z; s1.w += r1.w;
        s2.x += r2.x; s2.y += r2.y; s2.z += r2.z; s2.w += r2.w;
    }
}

// qkv: K/V (e in [512,1536)) for all 42 rows, Q (e in [0,512)) only for the 11
// needed rows. Wave = one (row, e). ln24 of previous layer folded in.
#define KV_WAVES (NROWS*1024)
#define Q_WAVES  (11*512)
__global__ void qkv_kernel(const float* __restrict__ features,
                           const float* __restrict__ role,
                           const float* __restrict__ ffprev,
                           const float* __restrict__ l2w, const float* __restrict__ l2b,
                           const float* __restrict__ l4w, const float* __restrict__ l4b,
                           const float* __restrict__ iw, const float* __restrict__ ib,
                           float* __restrict__ qkv, int l) {
    int gw = (blockIdx.x * blockDim.x + threadIdx.x) >> 6;
    int lane = threadIdx.x & 63;
    int row, e;
    if (gw < KV_WAVES) {
        row = gw >> 10;          // /1024
        e = 512 + (gw & 1023);
    } else {
        int g2 = gw - KV_WAVES;
        if (g2 >= Q_WAVES) return;
        row = NRQ[g2 >> 9];
        e = g2 & 511;
    }
    int b = row / NS, s = row - b * NS;
    float4 s1, s2;
    load_src(b, s, lane, l, features, role, ffprev, l2w, l2b, l4w, l4b, s1, s2);
    int d0 = lane * 8;
    const float* wr = iw + (size_t)e * ND + d0;
    float4 w1 = *(const float4*)wr;
    float4 w2 = *(const float4*)(wr + 4);
    float acc = s1.x*w1.x + s1.y*w1.y + s1.z*w1.z + s1.w*w1.w
              + s2.x*w2.x + s2.y*w2.y + s2.z*w2.z + s2.w*w2.w;
    acc = wave_sum(acc);
    if (lane == 0) qkv[(size_t)row * 1536 + e] = acc + ib[e];
}

// msg (+ inline attention) for the 11 needed rows only.
// Block = (needed-row, 64-wide e chunk). 88 blocks x 256 threads.
__global__ void msg_attn_kernel(const float* __restrict__ qkv,
                                const float* __restrict__ ow,
                                const float* __restrict__ ob,
                                float* __restrict__ msg) {
    int row = NRQ[blockIdx.x >> 3];
    int chunk = blockIdx.x & 7;
    int b = row / NS, s = row - b * NS;
    int t = threadIdx.x;
    __shared__ float ctx_s[ND];
    __shared__ float att_s[NH][NS];
    const float* qkvb = qkv + (size_t)b * NS * 1536;
    int h = t >> 5, l5 = t & 31;
    if (l5 < NS) {
        const float* qp = qkvb + (size_t)s * 1536 + h * HDIM;
        const float* kp = qkvb + (size_t)l5 * 1536 + ND + h * HDIM;
        float acc = 0.f;
        for (int d = 0; d < HDIM; d++) acc += qp[d] * kp[d];
        att_s[h][l5] = acc * 0.125f;
    }
    __syncthreads();
    if (l5 == 0) {
        float m = -1e30f;
        for (int j = 0; j < NS; j++) m = fmaxf(m, att_s[h][j]);
        float e[NS], sum = 0.f;
        for (int j = 0; j < NS; j++) { e[j] = expf(att_s[h][j] - m); sum += e[j]; }
        float inv = 1.f / sum;
        for (int j = 0; j < NS; j++) att_s[h][j] = e[j] * inv;
    }
    __syncthreads();
    {
        int d = l5 * 2;
        const float* vp = qkvb + 2*ND + h*HDIM + d;
        float a0 = 0.f, a1 = 0.f;
        for (int j = 0; j < NS; j++) {
            float aj = att_s[h][j];
            a0 += aj * vp[(size_t)j*1536];
            a1 += aj * vp[(size_t)j*1536 + 1];
        }
        ctx_s[h*HDIM + d] = a0;
        ctx_s[h*HDIM + d + 1] = a1;
    }
    __syncthreads();
    int wv = t >> 6, lane = t & 63;
    for (int i = 0; i < 16; i++) {
        int e = chunk*64 + wv*16 + i;
        float acc = dot512(ctx_s, ow + (size_t)e * ND, lane);
        acc = wave_sum(acc);
        if (lane == 0) msg[(size_t)row * ND + e] = acc + ob[e];
    }
}

// agg: one block (256 threads) per output j. j<512 -> verb(aggv), else noun(aggn).
__global__ void agg_kernel(const float* __restrict__ msg,
                           const float* __restrict__ aw1, const float* __restrict__ ab1,
                           const float* __restrict__ aw2, const float* __restrict__ ab2,
                           float* __restrict__ aggv, float* __restrict__ aggn) {
    int j = blockIdx.x, t = threadIdx.x;
    __shared__ float sd[4];
    float acc = 0.f;
    if (j < ND) {
        const float* wj = aw1 + (size_t)j * 2560;
        for (int c = 0; c < 5; c++) {
            const float* mp = msg + (size_t)(c+1) * NS * ND;
            acc += mp[t] * wj[c*512 + t] + mp[256 + t] * wj[c*512 + 256 + t];
        }
    } else {
        const float* wj = aw2 + (size_t)(j - ND) * 3072;
        for (int c = 0; c < 6; c++) {
            const float* mp = msg + (size_t)(c+1) * ND;
            acc += mp[t] * wj[c*512 + t] + mp[256 + t] * wj[c*512 + 256 + t];
        }
    }
    float v = wave_sum(acc);
    int lane = t & 63, wv = t >> 6;
    if (lane == 0) sd[wv] = v;
    __syncthreads();
    if (t == 0) {
        float s = sd[0] + sd[1] + sd[2] + sd[3];
        if (j < ND) aggv[j] = 1.f / (1.f + expf(-(s + ab1[j])));
        else        aggn[j - ND] = 1.f / (1.f + expf(-(s + ab2[j - ND])));
    }
}

// Build xln row r into LDS: xln = LN( cur_r + agg , lnw/lnb ), where
// cur_r = (l==0) ? features[r] : LN(ffprev[r], prev ln). Thread t handles t, t+256.
__device__ __forceinline__ void build_xln(int r, int l,
    const float* __restrict__ features, const float* __restrict__ ffprev,
    const float* __restrict__ lnpw, const float* __restrict__ lnpb,
    const float* __restrict__ agg,
    const float* __restrict__ lnw, const float* __restrict__ lnb,
    float* xs, float* sd)
{
    int t = threadIdx.x, lane = t & 63, wv = t >> 6;
    float x0, x1;
    if (l == 0) {
        x0 = features[r*ND + t];
        x1 = features[r*ND + 256 + t];
    } else {
        float f0 = ffprev[r*ND + t], f1 = ffprev[r*ND + 256 + t];
        float v = wave_sum(f0 + f1);
        if (lane == 0) sd[wv] = v;
        __syncthreads();
        float mu = (sd[0]+sd[1]+sd[2]+sd[3]) * (1.f/ND);
        __syncthreads();
        float d0 = f0 - mu, d1 = f1 - mu;
        v = wave_sum(d0*d0 + d1*d1);
        if (lane == 0) sd[wv] = v;
        __syncthreads();
        float var = (sd[0]+sd[1]+sd[2]+sd[3]) * (1.f/ND);
        float inv = rsqrtf(var + 1e-5f);
        x0 = d0*inv*lnpw[t]     + lnpb[t];
        x1 = d1*inv*lnpw[256+t] + lnpb[256+t];
        __syncthreads();
    }
    x0 += agg[t];
    x1 += agg[256 + t];
    float v = wave_sum(x0 + x1);
    if (lane == 0) sd[wv] = v;
    __syncthreads();
    float mu = (sd[0]+sd[1]+sd[2]+sd[3]) * (1.f/ND);
    __syncthreads();
    float d0 = x0 - mu, d1 = x1 - mu;
    v = wave_sum(d0*d0 + d1*d1);
    if (lane == 0) sd[wv] = v;
    __syncthreads();
    float var = (sd[0]+sd[1]+sd[2]+sd[3]) * (1.f/ND);
    float inv = rsqrtf(var + 1e-5f);
    xs[t]       = d0*inv*lnw[t]     + lnb[t];
    xs[256 + t] = d1*inv*lnw[256+t] + lnb[256+t];
    __syncthreads();
}

// ffa: h[r][f] = relu(xln_r . W1[f] + b1[f]).  Block = (r, 16-f chunk): 7*128 blocks.
__global__ void ffa_kernel(const float* __restrict__ features, const float* __restrict__ ffprev,
                           const float* __restrict__ l2pw, const float* __restrict__ l2pb,
                           const float* __restrict__ l4pw, const float* __restrict__ l4pb,
                           const float* __restrict__ aggv, const float* __restrict__ aggn,
                           const float* __restrict__ ln1w, const float* __restrict__ ln1b,
                           const float* __restrict__ ln3w, const float* __restrict__ ln3b,
                           const float* __restrict__ w11, const float* __restrict__ b11,
                           const float* __restrict__ w21, const float* __restrict__ b21,
                           float* __restrict__ hbuf, int l) {
    int r = blockIdx.x >> 7, fc = blockIdx.x & 127;
    __shared__ float xs[ND];
    __shared__ float sd[4];
    build_xln(r, l, features, ffprev,
              (r == 0) ? l4pw : l2pw, (r == 0) ? l4pb : l2pb,
              (r == 0) ? aggn : aggv,
              (r == 0) ? ln3w : ln1w, (r == 0) ? ln3b : ln1b, xs, sd);
    const float* W = (r == 0) ? w21 : w11;
    const float* B = (r == 0) ? b21 : b11;
    int wv = threadIdx.x >> 6, lane = threadIdx.x & 63;
    for (int i = 0; i < 4; i++) {
        int f = fc*16 + wv*4 + i;
        float acc = dot512(xs, W + (size_t)f * ND, lane);
        acc = wave_sum(acc);
        if (lane == 0) hbuf[r*NFF + f] = fmaxf(acc + B[f], 0.f);
    }
}

// ffb: ff[r][d] = xln_r[d] + h_r . W2[d] + b2[d].  Block = (r, 8-d chunk): 7*64 blocks.
__global__ void ffb_kernel(const float* __restrict__ features, const float* __restrict__ ffprev,
                           const float* __restrict__ l2pw, const float* __restrict__ l2pb,
                           const float* __restrict__ l4pw, const float* __restrict__ l4pb,
                           const float* __restrict__ aggv, const float* __restrict__ aggn,
                           const float* __restrict__ ln1w, const float* __restrict__ ln1b,
                           const float* __restrict__ ln3w, const float* __restrict__ ln3b,
                           const float* __restrict__ hbuf,
                           const float* __restrict__ w12, const float* __restrict__ b12,
                           const float* __restrict__ w22, const float* __restrict__ b22,
                           float* __restrict__ ff, int l) {
    int r = blockIdx.x >> 6, dc = blockIdx.x & 63;
    __shared__ float xs[ND];
    __shared__ float sd[4];
    build_xln(r, l, features, ffprev,
              (r == 0) ? l4pw : l2pw, (r == 0) ? l4pb : l2pb,
              (r == 0) ? aggn : aggv,
              (r == 0) ? ln3w : ln1w, (r == 0) ? ln3b : ln1b, xs, sd);
    const float* W = (r == 0) ? w22 : w12;
    const float* B = (r == 0) ? b22 : b12;
    const float* hr = hbuf + r * NFF;
    int wv = threadIdx.x >> 6, lane = threadIdx.x & 63;
    for (int i = 0; i < 2; i++) {
        int d = dc*8 + wv*2 + i;
        float acc = dot2048(hr, W + (size_t)d * NFF, lane);
        acc = wave_sum(acc);
        if (lane == 0) ff[r*ND + d] = xs[d] + acc + B[d];
    }
}

// final: out rows = LN(ff rows, ln2/ln4 of last layer)
__global__ void final_ln_kernel(const float* __restrict__ ff,
                                const float* __restrict__ l2w, const float* __restrict__ l2b,
                                const float* __restrict__ l4w, const float* __restrict__ l4b,
                                float* __restrict__ outp) {
    int r = blockIdx.x, t = threadIdx.x;
    const float* w  = (r == 0) ? l4w : l2w;
    const float* bb = (r == 0) ? l4b : l2b;
    float x0 = ff[r*ND + t], x1 = ff[r*ND + 256 + t];
    __shared__ float sd[4];
    int lane = t & 63, wv = t >> 6;
    float v = wave_sum(x0 + x1);
    if (lane == 0) sd[wv] = v;
    __syncthreads();
    float mu = (sd[0]+sd[1]+sd[2]+sd[3]) * (1.f/ND);
    __syncthreads();
    float d0 = x0 - mu, d1 = x1 - mu;
    v = wave_sum(d0*d0 + d1*d1);
    if (lane == 0) sd[wv] = v;
    __syncthreads();
    float var = (sd[0]+sd[1]+sd[2]+sd[3]) * (1.f/ND);
    float inv = rsqrtf(var + 1e-5f);
    outp[r*ND + t]       = d0*inv*w[t]     + bb[t];
    outp[r*ND + 256 + t] = d1*inv*w[256+t] + bb[256+t];
}

extern "C" void kernel_launch(void* const* d_in, const int* in_sizes, int n_in,
                              void* d_out, int out_size, void* d_ws, size_t ws_size,
                              hipStream_t stream) {
    const float* features = (const float*)d_in[0];
    const float* role     = (const float*)d_in[1];
    const float* in_w  = (const float*)d_in[2];
    const float* in_b  = (const float*)d_in[3];
    const float* out_w = (const float*)d_in[4];
    const float* out_b = (const float*)d_in[5];
    const float* ln1_w = (const float*)d_in[6];
    const float* ln1_b = (const float*)d_in[7];
    const float* ln2_w = (const float*)d_in[8];
    const float* ln2_b = (const float*)d_in[9];
    const float* ln3_w = (const float*)d_in[10];
    const float* ln3_b = (const float*)d_in[11];
    const float* ln4_w = (const float*)d_in[12];
    const float* ln4_b = (const float*)d_in[13];
    const float* f1_w1 = (const float*)d_in[14];
    const float* f1_b1 = (const float*)d_in[15];
    const float* f1_w2 = (const float*)d_in[16];
    const float* f1_b2 = (const float*)d_in[17];
    const float* f2_w1 = (const float*)d_in[18];
    const float* f2_b1 = (const float*)d_in[19];
    const float* f2_w2 = (const float*)d_in[20];
    const float* f2_b2 = (const float*)d_in[21];
    const float* a1_w  = (const float*)d_in[22];
    const float* a1_b  = (const float*)d_in[23];
    const float* a2_w  = (const float*)d_in[24];
    const float* a2_b  = (const float*)d_in[25];

    float* ws   = (float*)d_ws;
    float* qkv  = ws;                // 42*1536 = 64512
    float* msg  = qkv + 64512;       // 42*512  = 21504 (only 11 rows written)
    float* aggv = msg + 21504;       // 512
    float* aggn = aggv + 512;        // 512
    float* hbuf = aggn + 512;        // 7*2048 = 14336
    float* ffA  = hbuf + 14336;      // 3584
    float* ffB  = ffA + 3584;        // 3584
    float* ffb_[2] = {ffA, ffB};

    const int QKV_BLOCKS = (KV_WAVES + Q_WAVES) / 4;   // 12160

    for (int l = 0; l < NL; l++) {
        const float* ffprev = (l == 0) ? nullptr : ffb_[(l-1) & 1];
        float* ffcur = ffb_[l & 1];
        const float* l2pw = ln2_w + (size_t)((l > 0) ? l-1 : 0) * ND;
        const float* l2pb = ln2_b + (size_t)((l > 0) ? l-1 : 0) * ND;
        const float* l4pw = ln4_w + (size_t)((l > 0) ? l-1 : 0) * ND;
        const float* l4pb = ln4_b + (size_t)((l > 0) ? l-1 : 0) * ND;

        qkv_kernel<<<QKV_BLOCKS, 256, 0, stream>>>(
            features, role, ffprev, l2pw, l2pb, l4pw, l4pb,
            in_w + (size_t)l*1536*ND, in_b + (size_t)l*1536, qkv, l);
        msg_attn_kernel<<<11*8, 256, 0, stream>>>(
            qkv, out_w + (size_t)l*ND*ND, out_b + (size_t)l*ND, msg);
        agg_kernel<<<2*ND, 256, 0, stream>>>(
            msg, a1_w + (size_t)l*ND*2560, a1_b + (size_t)l*ND,
                 a2_w + (size_t)l*ND*3072, a2_b + (size_t)l*ND, aggv, aggn);
        ffa_kernel<<<NS*128, 256, 0, stream>>>(
            features, ffprev, l2pw, l2pb, l4pw, l4pb, aggv, aggn,
            ln1_w + (size_t)l*ND, ln1_b + (size_t)l*ND,
            ln3_w + (size_t)l*ND, ln3_b + (size_t)l*ND,
            f1_w1 + (size_t)l*NFF*ND, f1_b1 + (size_t)l*NFF,
            f2_w1 + (size_t)l*NFF*ND, f2_b1 + (size_t)l*NFF, hbuf, l);
        ffb_kernel<<<NS*64, 256, 0, stream>>>(
            features, ffprev, l2pw, l2pb, l4pw, l4pb, aggv, aggn,
            ln1_w + (size_t)l*ND, ln1_b + (size_t)l*ND,
            ln3_w + (size_t)l*ND, ln3_b + (size_t)l*ND,
            hbuf,
            f1_w2 + (size_t)l*ND*NFF, f1_b2 + (size_t)l*ND,
            f2_w2 + (size_t)l*ND*NFF, f2_b2 + (size_t)l*ND, ffcur, l);
    }
    final_ln_kernel<<<NS, 256, 0, stream>>>(
        ffb_[(NL-1) & 1],
        ln2_w + (size_t)(NL-1)*ND, ln2_b + (size_t)(NL-1)*ND,
        ln4_w + (size_t)(NL-1)*ND, ln4_b + (size_t)(NL-1)*ND,
        (float*)d_out);
}